// Round 4
// baseline (145.877 us; speedup 1.0000x reference)
//
#include <hip/hip_runtime.h>
#include <math.h>

// TemporalSNNClassifier — bit-exact fp32 emulation (absmax 0.0 since r2).
//
// r18: W2 -> 128 VGPRs. Grid-limited to 2 blocks/CU (512 blocks / 256 CU)
// = 2 waves/SIMD, so up to 256 VGPR/thread is FREE (r17 used only 84).
// Phase-B's 32 w2l b128 reads per thread per ts-group are uniform-per-
// half-wave: by the unified law each moves 64x16B = 1KB for 16B useful —
// 128KB of the 384KB LDS movement per block-ts-group, re-read 16x only
// because W2 wasn't in registers. Hoist: 32 float4 w2r[] per thread (own
// class row, loaded once from global), statically indexed by the unrolled
// gg loop. w2l LDS region + staging deleted. Arithmetic sequences
// unchanged -> absmax 0.0 preserved.
//
// r17 evidence: fusion 66+66 -> 92.5us in-kernel (phases of co-resident
// blocks overlap); ~50us/iter harness floor outside the kernel.
// r16b evidence: fma_mix cut tloop 82->66us, VALUBusy 85->61%.
// Unified law (r10+r12+m136): 16B-per-lane reads are NEVER deduplicated —
// wave-uniform b128 moves 64x16B serialized; b32 same-addr broadcast FREE.
//
// FROZEN numerics: k-ascending single-accumulator fmaf chains (GEMM1),
// h-ascending 0..127 chain per (row,class,t) via v_fma_mix_f32 over fp16
// spike pairs (exact for {0,1}, single f32 rounding == fmaf(spk,w,acc)),
// bias as one separate add, leaky update ((0.9f*mem)+cur)-reset with
// contraction off, spike <=> mem > 1.0f, reset_t == spk_{t-1}.

#define T_STEPS 64
#define IN_DIM  256
#define HID     128
#define NCLS    8

#define ROWS   32     // rows per block (both phases)
#define THR    256
#define A_KQ   16     // float4 k-quads per chunk (64 k)
#define RSTR   260    // pk row stride (u32); =4 mod 32 -> staggered banks

// pack two {0.0f,1.0f} spikes into one u32 as fp16 pair (lo=a, hi=b).
static __device__ __forceinline__ unsigned int pkspk(float a, float b) {
    auto h = __builtin_amdgcn_cvt_pkrtz(a, b);   // __fp16 ext_vector(2), 4B
    return __builtin_bit_cast(unsigned int, h);
}

__global__ __launch_bounds__(THR, 2)
void snn_fused(const float* __restrict__ x, const float* __restrict__ W1,
               const float* __restrict__ b1, const float* __restrict__ W2,
               const float* __restrict__ b2, float* __restrict__ out)
{
#pragma clang fp contract(off)
    __shared__ __align__(16) char smem[41728];
    float4 (* const w1c)[HID + 2] = (float4 (*)[HID + 2])smem;   // [16][130]
    float*        const xcf = (float*)(smem + 33280);            // 64*33
    unsigned int* const pk  = (unsigned int*)smem;               // 32*260
    float*        const wsl = (float*)smem;                      // 32*128

    const int tid  = threadIdx.x;
    const int lane = tid & 63;

    // ================= phase 1: cur1 GEMM (r15 verbatim) =================
    {
        const int wv = __builtin_amdgcn_readfirstlane(tid >> 6);   // 0..3
        const size_t rowg0 = (size_t)blockIdx.x * ROWS;

        float accL[8], accH[8];
        #pragma unroll
        for (int j = 0; j < 8; ++j) { accL[j] = 0.0f; accH[j] = 0.0f; }

        #pragma unroll 1
        for (int ch = 0; ch < 4; ++ch) {
            const int kbase = ch * (A_KQ * 4);
            // stage W1 chunk: 2048 float4, 8 per thread (coalesced per h-row)
            #pragma unroll
            for (int s = 0; s < 8; ++s) {
                const int idx = tid + s * THR;
                const int h = idx >> 4, kq = idx & 15;
                w1c[kq][h] = *(const float4*)(W1 + (size_t)h * IN_DIM + kbase + kq * 4);
            }
            // stage x chunk c-major: quad (rr,kq) -> xcf[(4kq+c)*33 + rr]
            #pragma unroll
            for (int s = 0; s < 2; ++s) {
                const int idx = tid + s * THR;
                const int rr = idx >> 4, kq = idx & 15;
                const float4 v = *(const float4*)(x + (rowg0 + rr) * IN_DIM + kbase + kq * 4);
                xcf[(4 * kq + 0) * 33 + rr] = v.x;
                xcf[(4 * kq + 1) * 33 + rr] = v.y;
                xcf[(4 * kq + 2) * 33 + rr] = v.z;
                xcf[(4 * kq + 3) * 33 + rr] = v.w;
            }
            __syncthreads();

            #pragma unroll 4
            for (int kq = 0; kq < A_KQ; ++kq) {
                const float4 wL = w1c[kq][lane];        // lane-contig 1KB
                const float4 wH = w1c[kq][64 + lane];
                #pragma unroll
                for (int j = 0; j < 8; ++j) {
                    const int rb = wv * 8 + j;
                    // 4 separate b32 broadcasts (132B apart -> no b128 merge)
                    const float x0 = xcf[(4 * kq + 0) * 33 + rb];
                    const float x1 = xcf[(4 * kq + 1) * 33 + rb];
                    const float x2 = xcf[(4 * kq + 2) * 33 + rb];
                    const float x3 = xcf[(4 * kq + 3) * 33 + rb];
                    float aL = accL[j], aH = accH[j];
                    aL = fmaf(x0, wL.x, aL);   // k ascending, single acc
                    aL = fmaf(x1, wL.y, aL);
                    aL = fmaf(x2, wL.z, aL);
                    aL = fmaf(x3, wL.w, aL);
                    aH = fmaf(x0, wH.x, aH);
                    aH = fmaf(x1, wH.y, aH);
                    aH = fmaf(x2, wH.z, aH);
                    aH = fmaf(x3, wH.w, aH);
                    accL[j] = aL; accH[j] = aH;
                }
            }
            __syncthreads();   // also fences w1c/xcf before re-stage / alias
        }

        // handoff: cur1 tile -> LDS (aliases dead w1c). Values bit-identical
        // to the old global ws path (same accL/accH + one rounded bias add).
        const float bL = b1[lane], bH = b1[64 + lane];
        #pragma unroll
        for (int j = 0; j < 8; ++j) {
            const int rr = wv * 8 + j;
            wsl[rr * HID + lane]      = accL[j] + bL;
            wsl[rr * HID + 64 + lane] = accH[j] + bH;
        }
    }

    // ================= phase 2: temporal loop =============
    const int r = tid >> 3;            // phase-a row 0..31
    const int q = tid & 7;             // phase-a h-block

    const int brow = lane & 31;
    const int bcls = 2 * (tid >> 6) + (lane >> 5);
    const float b2c = b2[bcls];

    // W2 row for this thread's class -> 128 VGPRs (loaded once from global;
    // free: grid-limited to 2 waves/SIMD so budget is 256 VGPR/thread).
    float4 w2r[32];
    {
        const float4* wg = (const float4*)(W2 + bcls * HID);
        #pragma unroll
        for (int g = 0; g < 32; ++g) w2r[g] = wg[g];
    }

    __syncthreads();   // wsl writes visible

    float cur1[16];
    {
        const float* src = wsl + r * HID + q * 16;
        #pragma unroll
        for (int i = 0; i < 4; ++i) {
            const float4 v = *(const float4*)(src + 4 * i);
            cur1[4*i+0] = v.x; cur1[4*i+1] = v.y;
            cur1[4*i+2] = v.z; cur1[4*i+3] = v.w;
        }
    }
    __syncthreads();   // cur1 read complete before pk overwrites wsl region

    float mem1[16], spk1[16];
    #pragma unroll
    for (int i = 0; i < 16; ++i) { mem1[i] = 0.0f; spk1[i] = 0.0f; }
    float m2 = 0.0f, r2v = 0.0f, o = 0.0f;

    #pragma unroll 1
    for (int ts = 0; ts < T_STEPS; ts += 4) {
        #pragma unroll
        for (int j = 0; j < 4; ++j) {
            #pragma unroll
            for (int i = 0; i < 16; ++i) {
                float tmp = 0.9f * mem1[i];   // rounded mul
                tmp = tmp + cur1[i];          // rounded add
                float m = tmp - spk1[i];      // rounded sub
                mem1[i] = m;
                spk1[i] = (m > 1.0f) ? 1.0f : 0.0f;
            }
            unsigned int* dst = &pk[r * RSTR + j * 64 + q * 8];
            #pragma unroll
            for (int s = 0; s < 2; ++s) {
                uint4 pv;
                pv.x = pkspk(spk1[8*s+0], spk1[8*s+1]);   // lo=even h, hi=odd h
                pv.y = pkspk(spk1[8*s+2], spk1[8*s+3]);
                pv.z = pkspk(spk1[8*s+4], spk1[8*s+5]);
                pv.w = pkspk(spk1[8*s+6], spk1[8*s+7]);
                *(uint4*)(dst + 4 * s) = pv;
            }
        }
        __syncthreads();

        float a0 = 0.0f, a1 = 0.0f, a2 = 0.0f, a3 = 0.0f;
        const unsigned int* src = &pk[brow * RSTR];
        // v_fma_mix_f32: src0 = fp16 half of packed word (exact 0/1 -> f32),
        // src1 = f32 W2 (VGPR), src2 = f32 acc; single f32 rounding —
        // bit-identical to fmaf(spk, w, acc), h-ascending. LO=even h, HI=odd.
#define FMIX_LO(A, P, W) \
        asm("v_fma_mix_f32 %0, %1, %2, %0 op_sel_hi:[1,0,0]" \
            : "+v"(A) : "v"(P), "v"(W));
#define FMIX_HI(A, P, W) \
        asm("v_fma_mix_f32 %0, %1, %2, %0 op_sel:[1,0,0] op_sel_hi:[1,0,0]" \
            : "+v"(A) : "v"(P), "v"(W));
#define TR(A, P) \
        FMIX_LO(A, P.x, wA.x) FMIX_HI(A, P.x, wA.y) \
        FMIX_LO(A, P.y, wA.z) FMIX_HI(A, P.y, wA.w) \
        FMIX_LO(A, P.z, wB.x) FMIX_HI(A, P.z, wB.y) \
        FMIX_LO(A, P.w, wB.z) FMIX_HI(A, P.w, wB.w)
        #pragma unroll
        for (int gg = 0; gg < 16; ++gg) {
            const float4 wA = w2r[2 * gg];
            const float4 wB = w2r[2 * gg + 1];
            const uint4 p0 = *(const uint4*)(src + 0 * 64 + 4 * gg);
            const uint4 p1 = *(const uint4*)(src + 1 * 64 + 4 * gg);
            const uint4 p2 = *(const uint4*)(src + 2 * 64 + 4 * gg);
            const uint4 p3 = *(const uint4*)(src + 3 * 64 + 4 * gg);
            TR(a0, p0) TR(a1, p1) TR(a2, p2) TR(a3, p3)
        }
#undef TR
#undef FMIX_HI
#undef FMIX_LO
        __syncthreads();

        const float aa[4] = {a0, a1, a2, a3};
        #pragma unroll
        for (int j = 0; j < 4; ++j) {
            const float c2 = aa[j] + b2c;
            float t2 = 0.9f * m2; t2 = t2 + c2; m2 = t2 - r2v;
            r2v = (m2 > 1.0f) ? 1.0f : 0.0f;
            o = o + r2v;
        }
    }

    out[((size_t)blockIdx.x * ROWS + brow) * NCLS + bcls] = o;
}

extern "C" void kernel_launch(void* const* d_in, const int* in_sizes, int n_in,
                              void* d_out, int out_size, void* d_ws, size_t ws_size,
                              hipStream_t stream) {
    const float* x  = (const float*)d_in[0];
    const float* W1 = (const float*)d_in[1];
    const float* b1 = (const float*)d_in[2];
    const float* W2 = (const float*)d_in[3];
    const float* b2 = (const float*)d_in[4];
    float* out = (float*)d_out;
    (void)d_ws; (void)ws_size;

    const int batch = in_sizes[0] / IN_DIM;          // 16384
    snn_fused<<<batch / ROWS, THR, 0, stream>>>(x, W1, b1, W2, b2, out);
}

// Round 5
// 144.630 us; speedup vs baseline: 1.0086x; 1.0086x over previous
//
#include <hip/hip_runtime.h>
#include <math.h>

// TemporalSNNClassifier — bit-exact fp32 emulation (absmax 0.0 since r2).
//
// r19: GEMM1 x via the SCALAR pipe. All 4 prior GEMM1 implementations
// (invariant ~81us) delivered x through the vector path (LDS broadcasts or
// VMEM), paying 2048 ds_read_b32 + staging per wave. But every x index in
// the inner loop is wave-uniform -> s_load_dwordx4 into SGPRs (SMEM pipe,
// one copy, no per-lane movement), consumed directly as the 1-allowed-SGPR
// operand of v_fma_f32. Deletes ALL xcf LDS traffic, staging, addressing.
// Forced via inline asm: 8x s_load_dwordx4 + single lgkmcnt(0) in ONE asm
// block (data-deps order consumers; early-clobber outputs). Identical ops,
// identical order -> absmax 0.0 preserved.
//
// r18 evidence: W2->VGPR was null (-2us): phase-B not limited by w2 reads.
// r17 evidence: fusion 66+66 -> 92.5us in-kernel; ~50us/iter harness floor.
// r16b evidence: fma_mix cut tloop 82->66us, VALUBusy 85->61%.
// Unified law (r10+r12+m136): 16B-per-lane VECTOR reads are NEVER
// deduplicated — wave-uniform b128 moves 64x16B serialized; b32 same-addr
// broadcast FREE; SMEM pipe untested until now.
//
// FROZEN numerics: k-ascending single-accumulator fmaf chains (GEMM1),
// h-ascending 0..127 chain per (row,class,t) via v_fma_mix_f32 over fp16
// spike pairs (exact for {0,1}, single f32 rounding == fmaf(spk,w,acc)),
// bias as one separate add, leaky update ((0.9f*mem)+cur)-reset with
// contraction off, spike <=> mem > 1.0f, reset_t == spk_{t-1}.

#define T_STEPS 64
#define IN_DIM  256
#define HID     128
#define NCLS    8

#define ROWS   32     // rows per block (both phases)
#define THR    256
#define A_KQ   16     // float4 k-quads per chunk (64 k)
#define RSTR   260    // pk row stride (u32); =4 mod 32 -> staggered banks

typedef float f32x4 __attribute__((ext_vector_type(4)));

// pack two {0.0f,1.0f} spikes into one u32 as fp16 pair (lo=a, hi=b).
static __device__ __forceinline__ unsigned int pkspk(float a, float b) {
    auto h = __builtin_amdgcn_cvt_pkrtz(a, b);   // __fp16 ext_vector(2), 4B
    return __builtin_bit_cast(unsigned int, h);
}

__global__ __launch_bounds__(THR, 2)
void snn_fused(const float* __restrict__ x, const float* __restrict__ W1,
               const float* __restrict__ b1, const float* __restrict__ W2,
               const float* __restrict__ b2, float* __restrict__ out)
{
#pragma clang fp contract(off)
    __shared__ __align__(16) char smem[33280];
    float4 (* const w1c)[HID + 2] = (float4 (*)[HID + 2])smem;   // [16][130]
    unsigned int* const pk  = (unsigned int*)smem;               // 32*260
    float*        const wsl = (float*)smem;                      // 32*128

    const int tid  = threadIdx.x;
    const int lane = tid & 63;

    // ================= phase 1: cur1 GEMM (x via SMEM) ===================
    {
        const int wv = __builtin_amdgcn_readfirstlane(tid >> 6);   // 0..3
        const size_t rowg0 = (size_t)blockIdx.x * ROWS;
        // per-wave x base: rows wv*8 .. wv*8+7 (uniform)
        const float* xb = x + (rowg0 + (size_t)wv * 8) * IN_DIM;

        float accL[8], accH[8];
        #pragma unroll
        for (int j = 0; j < 8; ++j) { accL[j] = 0.0f; accH[j] = 0.0f; }

        #pragma unroll 1
        for (int ch = 0; ch < 4; ++ch) {
            const int kbase = ch * (A_KQ * 4);
            // stage W1 chunk: 2048 float4, 8 per thread (coalesced per h-row)
            #pragma unroll
            for (int s = 0; s < 8; ++s) {
                const int idx = tid + s * THR;
                const int h = idx >> 4, kq = idx & 15;
                w1c[kq][h] = *(const float4*)(W1 + (size_t)h * IN_DIM + kbase + kq * 4);
            }
            __syncthreads();

            const float* xbc = xb + kbase;
            #pragma unroll 4
            for (int kq = 0; kq < A_KQ; ++kq) {
                // 8 rows' k-quads for this kq -> SGPRs (one wait for all 8).
                // Offsets: row j is j*IN_DIM*4 = j*0x400 bytes from xkq.
                const float* xkq = xbc + kq * 4;
                f32x4 q0, q1, q2, q3, q4, q5, q6, q7;
                asm volatile(
                    "s_load_dwordx4 %0, %8, 0x0\n\t"
                    "s_load_dwordx4 %1, %8, 0x400\n\t"
                    "s_load_dwordx4 %2, %8, 0x800\n\t"
                    "s_load_dwordx4 %3, %8, 0xc00\n\t"
                    "s_load_dwordx4 %4, %8, 0x1000\n\t"
                    "s_load_dwordx4 %5, %8, 0x1400\n\t"
                    "s_load_dwordx4 %6, %8, 0x1800\n\t"
                    "s_load_dwordx4 %7, %8, 0x1c00\n\t"
                    "s_waitcnt lgkmcnt(0)"
                    : "=&s"(q0), "=&s"(q1), "=&s"(q2), "=&s"(q3),
                      "=&s"(q4), "=&s"(q5), "=&s"(q6), "=&s"(q7)
                    : "s"(xkq));

                const float4 wL = w1c[kq][lane];        // lane-contig 1KB
                const float4 wH = w1c[kq][64 + lane];
                // k ascending, single acc per (row, h) — order unchanged.
#define ROWFMA(J, XQ) { \
                float aL = accL[J], aH = accH[J]; \
                aL = fmaf(XQ.x, wL.x, aL); \
                aL = fmaf(XQ.y, wL.y, aL); \
                aL = fmaf(XQ.z, wL.z, aL); \
                aL = fmaf(XQ.w, wL.w, aL); \
                aH = fmaf(XQ.x, wH.x, aH); \
                aH = fmaf(XQ.y, wH.y, aH); \
                aH = fmaf(XQ.z, wH.z, aH); \
                aH = fmaf(XQ.w, wH.w, aH); \
                accL[J] = aL; accH[J] = aH; }
                ROWFMA(0, q0) ROWFMA(1, q1) ROWFMA(2, q2) ROWFMA(3, q3)
                ROWFMA(4, q4) ROWFMA(5, q5) ROWFMA(6, q6) ROWFMA(7, q7)
#undef ROWFMA
            }
            __syncthreads();   // w1c consumed before re-stage / alias
        }

        // handoff: cur1 tile -> LDS (aliases dead w1c). Values bit-identical
        // to the old global ws path (same accL/accH + one rounded bias add).
        const float bL = b1[lane], bH = b1[64 + lane];
        #pragma unroll
        for (int j = 0; j < 8; ++j) {
            const int rr = wv * 8 + j;
            wsl[rr * HID + lane]      = accL[j] + bL;
            wsl[rr * HID + 64 + lane] = accH[j] + bH;
        }
    }

    // ================= phase 2: temporal loop (r18 verbatim) =============
    const int r = tid >> 3;            // phase-a row 0..31
    const int q = tid & 7;             // phase-a h-block

    const int brow = lane & 31;
    const int bcls = 2 * (tid >> 6) + (lane >> 5);
    const float b2c = b2[bcls];

    // W2 row for this thread's class -> VGPRs (grid-limited 2 waves/SIMD,
    // so up to 256 VGPR/thread is free).
    float4 w2r[32];
    {
        const float4* wg = (const float4*)(W2 + bcls * HID);
        #pragma unroll
        for (int g = 0; g < 32; ++g) w2r[g] = wg[g];
    }

    __syncthreads();   // wsl writes visible

    float cur1[16];
    {
        const float* src = wsl + r * HID + q * 16;
        #pragma unroll
        for (int i = 0; i < 4; ++i) {
            const float4 v = *(const float4*)(src + 4 * i);
            cur1[4*i+0] = v.x; cur1[4*i+1] = v.y;
            cur1[4*i+2] = v.z; cur1[4*i+3] = v.w;
        }
    }
    __syncthreads();   // cur1 read complete before pk overwrites wsl region

    float mem1[16], spk1[16];
    #pragma unroll
    for (int i = 0; i < 16; ++i) { mem1[i] = 0.0f; spk1[i] = 0.0f; }
    float m2 = 0.0f, r2v = 0.0f, o = 0.0f;

    #pragma unroll 1
    for (int ts = 0; ts < T_STEPS; ts += 4) {
        #pragma unroll
        for (int j = 0; j < 4; ++j) {
            #pragma unroll
            for (int i = 0; i < 16; ++i) {
                float tmp = 0.9f * mem1[i];   // rounded mul
                tmp = tmp + cur1[i];          // rounded add
                float m = tmp - spk1[i];      // rounded sub
                mem1[i] = m;
                spk1[i] = (m > 1.0f) ? 1.0f : 0.0f;
            }
            unsigned int* dst = &pk[r * RSTR + j * 64 + q * 8];
            #pragma unroll
            for (int s = 0; s < 2; ++s) {
                uint4 pv;
                pv.x = pkspk(spk1[8*s+0], spk1[8*s+1]);   // lo=even h, hi=odd h
                pv.y = pkspk(spk1[8*s+2], spk1[8*s+3]);
                pv.z = pkspk(spk1[8*s+4], spk1[8*s+5]);
                pv.w = pkspk(spk1[8*s+6], spk1[8*s+7]);
                *(uint4*)(dst + 4 * s) = pv;
            }
        }
        __syncthreads();

        float a0 = 0.0f, a1 = 0.0f, a2 = 0.0f, a3 = 0.0f;
        const unsigned int* src = &pk[brow * RSTR];
        // v_fma_mix_f32: src0 = fp16 half of packed word (exact 0/1 -> f32),
        // src1 = f32 W2 (VGPR), src2 = f32 acc; single f32 rounding —
        // bit-identical to fmaf(spk, w, acc), h-ascending. LO=even h, HI=odd.
#define FMIX_LO(A, P, W) \
        asm("v_fma_mix_f32 %0, %1, %2, %0 op_sel_hi:[1,0,0]" \
            : "+v"(A) : "v"(P), "v"(W));
#define FMIX_HI(A, P, W) \
        asm("v_fma_mix_f32 %0, %1, %2, %0 op_sel:[1,0,0] op_sel_hi:[1,0,0]" \
            : "+v"(A) : "v"(P), "v"(W));
#define TR(A, P) \
        FMIX_LO(A, P.x, wA.x) FMIX_HI(A, P.x, wA.y) \
        FMIX_LO(A, P.y, wA.z) FMIX_HI(A, P.y, wA.w) \
        FMIX_LO(A, P.z, wB.x) FMIX_HI(A, P.z, wB.y) \
        FMIX_LO(A, P.w, wB.z) FMIX_HI(A, P.w, wB.w)
        #pragma unroll
        for (int gg = 0; gg < 16; ++gg) {
            const float4 wA = w2r[2 * gg];
            const float4 wB = w2r[2 * gg + 1];
            const uint4 p0 = *(const uint4*)(src + 0 * 64 + 4 * gg);
            const uint4 p1 = *(const uint4*)(src + 1 * 64 + 4 * gg);
            const uint4 p2 = *(const uint4*)(src + 2 * 64 + 4 * gg);
            const uint4 p3 = *(const uint4*)(src + 3 * 64 + 4 * gg);
            TR(a0, p0) TR(a1, p1) TR(a2, p2) TR(a3, p3)
        }
#undef TR
#undef FMIX_HI
#undef FMIX_LO
        __syncthreads();

        const float aa[4] = {a0, a1, a2, a3};
        #pragma unroll
        for (int j = 0; j < 4; ++j) {
            const float c2 = aa[j] + b2c;
            float t2 = 0.9f * m2; t2 = t2 + c2; m2 = t2 - r2v;
            r2v = (m2 > 1.0f) ? 1.0f : 0.0f;
            o = o + r2v;
        }
    }

    out[((size_t)blockIdx.x * ROWS + brow) * NCLS + bcls] = o;
}

extern "C" void kernel_launch(void* const* d_in, const int* in_sizes, int n_in,
                              void* d_out, int out_size, void* d_ws, size_t ws_size,
                              hipStream_t stream) {
    const float* x  = (const float*)d_in[0];
    const float* W1 = (const float*)d_in[1];
    const float* b1 = (const float*)d_in[2];
    const float* W2 = (const float*)d_in[3];
    const float* b2 = (const float*)d_in[4];
    float* out = (float*)d_out;
    (void)d_ws; (void)ws_size;

    const int batch = in_sizes[0] / IN_DIM;          // 16384
    snn_fused<<<batch / ROWS, THR, 0, stream>>>(x, W1, b1, W2, b2, out);
}